// Round 1
// baseline (70.100 us; speedup 1.0000x reference)
//
#include <hip/hip_runtime.h>

// EMA with mask-gated carry along T.
// x: (B=32, T=4096, D=256) f32, mask: (B, T) i32, out: (B, T, D) f32.
// Recurrence is affine: new = a_t*prev + c_t, a_t/c_t wave-uniform per t.
// 3-pass chunked scan: local reduce -> chunk-chain scan -> local rescan.

constexpr int BATCH = 32;
constexpr int TLEN  = 4096;
constexpr int DDIM  = 256;
constexpr int CHUNKS = 64;              // chunks along T
constexpr int CLEN   = TLEN / CHUNKS;   // 64
constexpr int DV     = DDIM / 4;        // 64 float4 lanes

#define EMA_ALPHA 0.2f
#define EMA_OMA   0.8f

// Pass 1: per (b, chunk) compute composed affine (A scalar, B vector) assuming prev=0.
__global__ __launch_bounds__(64)
void ema_pass1(const float4* __restrict__ x, const int* __restrict__ mask,
               float* __restrict__ Abuf, float4* __restrict__ Bbuf) {
    const int blk = blockIdx.x;          // b*CHUNKS + c
    const int b = blk / CHUNKS;
    const int c = blk % CHUNKS;
    const int tid = threadIdx.x;         // 0..63 (d4)

    __shared__ int smask[CLEN];
    if (tid < CLEN) smask[tid] = mask[b * TLEN + c * CLEN + tid];
    __syncthreads();

    float A = 1.0f;
    float4 Bv = make_float4(0.f, 0.f, 0.f, 0.f);
    const float4* xp = x + (size_t)(b * TLEN + c * CLEN) * DV + tid;
    const bool c0 = (c == 0);

    #pragma unroll 8
    for (int i = 0; i < CLEN; ++i) {
        float4 xv = xp[(size_t)i * DV];
        const int v = smask[i];
        float a  = v ? EMA_OMA   : 1.0f;
        float cf = v ? EMA_ALPHA : 0.0f;
        if (c0 && i == 0) { a = 0.0f; cf = 1.0f; }   // t==0: ema0 = x0 unconditionally
        Bv.x = a * Bv.x + cf * xv.x;
        Bv.y = a * Bv.y + cf * xv.y;
        Bv.z = a * Bv.z + cf * xv.z;
        Bv.w = a * Bv.w + cf * xv.w;
        A *= a;
    }
    Bbuf[(size_t)blk * DV + tid] = Bv;
    if (tid == 0) Abuf[blk] = A;
}

// Pass 2: per (b, d4) sequentially chain the CHUNKS affine states;
// emit the chunk-entry carry P[b,c,d4].
__global__ __launch_bounds__(64)
void ema_pass2(const float* __restrict__ Abuf, const float4* __restrict__ Bbuf,
               float4* __restrict__ Pbuf) {
    const int b = blockIdx.x;
    const int tid = threadIdx.x;         // d4

    __shared__ float sA[CHUNKS];
    if (tid < CHUNKS) sA[tid] = Abuf[b * CHUNKS + tid];
    __syncthreads();

    float4 p = make_float4(0.f, 0.f, 0.f, 0.f);
    for (int c = 0; c < CHUNKS; ++c) {
        const size_t idx = (size_t)(b * CHUNKS + c) * DV + tid;
        Pbuf[idx] = p;                   // carry entering chunk c
        float4 Bv = Bbuf[idx];
        const float a = sA[c];
        p.x = a * p.x + Bv.x;
        p.y = a * p.y + Bv.y;
        p.z = a * p.z + Bv.z;
        p.w = a * p.w + Bv.w;
    }
}

// Pass 3: per (b, chunk) rescan x starting from the correct carry, write out.
__global__ __launch_bounds__(64)
void ema_pass3(const float4* __restrict__ x, const int* __restrict__ mask,
               const float4* __restrict__ Pbuf, float4* __restrict__ out) {
    const int blk = blockIdx.x;
    const int b = blk / CHUNKS;
    const int c = blk % CHUNKS;
    const int tid = threadIdx.x;

    __shared__ int smask[CLEN];
    if (tid < CLEN) smask[tid] = mask[b * TLEN + c * CLEN + tid];
    __syncthreads();

    float4 p = Pbuf[(size_t)blk * DV + tid];
    const size_t base = (size_t)(b * TLEN + c * CLEN) * DV + tid;
    const bool c0 = (c == 0);

    #pragma unroll 8
    for (int i = 0; i < CLEN; ++i) {
        float4 xv = x[base + (size_t)i * DV];
        const int v = smask[i];
        float a  = v ? EMA_OMA   : 1.0f;
        float cf = v ? EMA_ALPHA : 0.0f;
        if (c0 && i == 0) { a = 0.0f; cf = 1.0f; }
        p.x = a * p.x + cf * xv.x;
        p.y = a * p.y + cf * xv.y;
        p.z = a * p.z + cf * xv.z;
        p.w = a * p.w + cf * xv.w;
        out[base + (size_t)i * DV] = p;
    }
}

extern "C" void kernel_launch(void* const* d_in, const int* in_sizes, int n_in,
                              void* d_out, int out_size, void* d_ws, size_t ws_size,
                              hipStream_t stream) {
    const float4* x   = (const float4*)d_in[0];
    const int* mask   = (const int*)d_in[1];
    float4* out       = (float4*)d_out;

    // Workspace layout (16B-aligned slabs):
    //   Abuf: B*CHUNKS floats            =  8 KB
    //   Bbuf: B*CHUNKS*DV float4         =  2 MB
    //   Pbuf: B*CHUNKS*DV float4         =  2 MB
    char* ws = (char*)d_ws;
    float*  Abuf = (float*)ws;
    float4* Bbuf = (float4*)(ws + 16 * 1024);
    float4* Pbuf = (float4*)(ws + 16 * 1024 + (size_t)BATCH * CHUNKS * DV * sizeof(float4));

    ema_pass1<<<BATCH * CHUNKS, 64, 0, stream>>>(x, mask, Abuf, Bbuf);
    ema_pass2<<<BATCH, 64, 0, stream>>>(Abuf, Bbuf, Pbuf);
    ema_pass3<<<BATCH * CHUNKS, 64, 0, stream>>>(x, mask, Pbuf, out);
}